// Round 4
// baseline (132.592 us; speedup 1.0000x reference)
//
#include <hip/hip_runtime.h>

// Problem constants (from reference)
constexpr int B = 128, T = 12, V = 512, P = 40;
constexpr int CHUNKS = 8;        // V split across 8 blocks per batch
constexpr int VPB = V / CHUNKS;  // 64 v's per block, 4 threads per v
#define MAP_THRESH 0.5f
#define DIS_THRESH 1.0f
#define MASK_FILL  1000000.0f

// transform: x = l*30 - 15 ; y = l*60 - 30  (two-step rounding, no FMA, to match np)
__device__ __forceinline__ float txf(float l) { return __fadd_rn(__fmul_rn(l, 30.0f), -15.0f); }
__device__ __forceinline__ float tyf(float l) { return __fadd_rn(__fmul_rn(l, 60.0f), -30.0f); }

// block-uniform float -> SGPR (breaks the ds_read dependence in the hot loop)
__device__ __forceinline__ float rfl(float x) {
    return __int_as_float(__builtin_amdgcn_readfirstlane(__float_as_int(x)));
}

__device__ __forceinline__ float ld_agent_f(const float* p) {
    return __hip_atomic_load(p, __ATOMIC_RELAXED, __HIP_MEMORY_SCOPE_AGENT);
}
__device__ __forceinline__ int ld_agent_i(const int* p) {
    return __hip_atomic_load(p, __ATOMIC_RELAXED, __HIP_MEMORY_SCOPE_AGENT);
}

// ws layout (bytes):
//   [0,512)    int cnt_b[B]      -- zeroed by memset
//   [512,516)  int cnt_global    -- zeroed by memset
//   [1024,..)  float ws_val[B*T*CHUNKS] ; int ws_idx[B*T*CHUNKS] ; float ws_part[B]

// grid = B*CHUNKS blocks of 256. Phase A: block (b,c) -> per-t min+argmin over
// its 64 v's (4 threads/v, 10 pts each). Phase B: last block per b -> combine
// 8 chunks (ascending -> first-index ties), intersections, weighted per-b sum.
// Phase C: globally last -> deterministic tree-sum of 128 partials.
__global__ __launch_bounds__(256) void fused_kernel(
    const float* __restrict__ ego,     // B,T,2
    const float* __restrict__ lanes,   // B,V,P,2
    const float* __restrict__ scores,  // B,V,3
    const float* __restrict__ weight,  // B,T
    int*   __restrict__ cnt_b,         // B
    int*   __restrict__ cnt_global,
    float* __restrict__ ws_val,        // B*T*CHUNKS
    int*   __restrict__ ws_idx,        // B*T*CHUNKS
    float* __restrict__ ws_part,       // B
    float* __restrict__ out)
{
    const int blk = blockIdx.x;
    const int b = blk / CHUNKS, c = blk % CHUNKS;
    const int tid = threadIdx.x;
    const int vl = tid >> 2;   // 0..63  v within chunk
    const int pp = tid & 3;    // point-chunk: float4s {pp, 4+pp, 8+pp, 12+pp, 16+pp}
    const int v = c * VPB + vl;

    __shared__ float s_px[T + 1], s_py[T + 1];
    if (tid == 0) {
        float cx = 0.f, cy = 0.f;
        s_px[0] = 0.f; s_py[0] = 0.f;
        for (int t = 0; t < T; ++t) {  // sequential fp32 cumsum, matches np
            cx = __fadd_rn(cx, ego[(b * T + t) * 2 + 0]);
            cy = __fadd_rn(cy, ego[(b * T + t) * 2 + 1]);
            s_px[t + 1] = cx; s_py[t + 1] = cy;
        }
    }
    __syncthreads();

    // block-uniform trajectory -> SGPRs
    float px[T], py[T];
#pragma unroll
    for (int t = 0; t < T; ++t) { px[t] = rfl(s_px[t + 1]); py[t] = rfl(s_py[t + 1]); }

    // ---------------- Phase A: per-thread min over 10 points ----------------
    float minsq[T];
    const bool masked = scores[(size_t)(b * V + v) * 3 + 2] < MAP_THRESH;  // not_bound
    if (masked) {
        // all P points are exactly (1e6, 1e6)
#pragma unroll
        for (int t = 0; t < T; ++t) {
            float dx = __fsub_rn(px[t], MASK_FILL);
            float dy = __fsub_rn(py[t], MASK_FILL);
            minsq[t] = __fadd_rn(__fmul_rn(dx, dx), __fmul_rn(dy, dy));
        }
    } else {
#pragma unroll
        for (int t = 0; t < T; ++t) minsq[t] = 3.4e38f;
        const float4* lp = (const float4*)(lanes + (size_t)(b * V + v) * P * 2);
#pragma unroll
        for (int j = 0; j < 5; ++j) {   // 5 independent float4 loads, contiguous per 4-thread group
            float4 f = lp[4 * j + pp];
            float x0 = txf(f.x), y0 = tyf(f.y);
            float x1 = txf(f.z), y1 = tyf(f.w);
#pragma unroll
            for (int t = 0; t < T; ++t) {
                float dx = __fsub_rn(px[t], x0);
                float dy = __fsub_rn(py[t], y0);
                float d2 = __fadd_rn(__fmul_rn(dx, dx), __fmul_rn(dy, dy));
                minsq[t] = fminf(minsq[t], d2);
                dx = __fsub_rn(px[t], x1);
                dy = __fsub_rn(py[t], y1);
                d2 = __fadd_rn(__fmul_rn(dx, dx), __fmul_rn(dy, dy));
                minsq[t] = fminf(minsq[t], d2);
            }
        }
    }

    // combine the 4 point-chunks of each v (adjacent lanes, in-wave)
#pragma unroll
    for (int t = 0; t < T; ++t) {
        minsq[t] = fminf(minsq[t], __shfl_xor(minsq[t], 1));
        minsq[t] = fminf(minsq[t], __shfl_xor(minsq[t], 2));
    }

    // sqrt is monotone under RN: sqrt(min) == min(sqrt); compare sqrt'd values
    // so the v-argmin order matches the reference's argmin over norms.
    __shared__ float rv[T][VPB];
    __shared__ int   ri[T][VPB];
    if (pp == 0) {
#pragma unroll
        for (int t = 0; t < T; ++t) { rv[t][vl] = sqrtf(minsq[t]); ri[t][vl] = v; }
    }
    __syncthreads();
    for (int s = VPB / 2; s > 0; s >>= 1) {
        if (tid < s) {
#pragma unroll
            for (int t = 0; t < T; ++t) {
                float v1 = rv[t][tid + s]; int i1 = ri[t][tid + s];
                float v0 = rv[t][tid];     int i0 = ri[t][tid];
                if (v1 < v0 || (v1 == v0 && i1 < i0)) { rv[t][tid] = v1; ri[t][tid] = i1; }
            }
        }
        __syncthreads();
    }
    if (tid < T) {
        ws_val[(b * T + tid) * CHUNKS + c] = rv[tid][0];
        ws_idx[(b * T + tid) * CHUNKS + c] = ri[tid][0];
    }

    // release our chunk, detect whether we're the last block for this b
    __shared__ int s_last;
    if (tid == 0) {
        __threadfence();
        int old = atomicAdd(&cnt_b[b], 1);
        s_last = (old == CHUNKS - 1);
    }
    __syncthreads();
    if (!s_last) return;
    __threadfence();  // acquire other chunks' writes

    // ---------------- Phase B: combine + intersections + per-b sum ----------------
    __shared__ float s_md[T];
    __shared__ int   s_vm[T];
    __shared__ int   s_cross[T];
    if (tid < T) {
        float v0 = ld_agent_f(&ws_val[(b * T + tid) * CHUNKS + 0]);
        int   i0 = ld_agent_i(&ws_idx[(b * T + tid) * CHUNKS + 0]);
        for (int cc = 1; cc < CHUNKS; ++cc) {  // ascending -> strict < keeps first index
            float v1 = ld_agent_f(&ws_val[(b * T + tid) * CHUNKS + cc]);
            int   i1 = ld_agent_i(&ws_idx[(b * T + tid) * CHUNKS + cc]);
            if (v1 < v0) { v0 = v1; i0 = i1; }
        }
        s_md[tid] = v0; s_vm[tid] = i0;
        s_cross[tid] = 0;
    }
    __syncthreads();

    for (int w = tid; w < T * (P - 1); w += 256) {
        int t = w / (P - 1), p = w % (P - 1);
        int vw = s_vm[t];
        // masked lane -> all points identical -> det == 0 -> never intersects
        if (scores[(size_t)(b * V + vw) * 3 + 2] < MAP_THRESH) continue;
        const float* lp = lanes + (size_t)(b * V + vw) * P * 2 + (size_t)p * 2;
        float bx0 = txf(lp[0]), by0 = tyf(lp[1]);
        float bx1 = txf(lp[2]), by1 = tyf(lp[3]);
        float sx = s_px[t],     sy = s_py[t];      // starts[t]
        float ex = s_px[t + 1], ey = s_py[t + 1];  // pred[t]
        float d1x = __fsub_rn(ex, sx),  d1y = __fsub_rn(ey, sy);
        float d2x = __fsub_rn(bx1, bx0), d2y = __fsub_rn(by1, by0);
        float det = __fsub_rn(__fmul_rn(d1x, d2y), __fmul_rn(d2x, d1y));
        if (det != 0.0f) {
            float dx = __fsub_rn(bx0, sx), dy = __fsub_rn(by0, sy);
            float t1 = __fdiv_rn(__fsub_rn(__fmul_rn(dx, d2y), __fmul_rn(dy, d2x)), det);
            float t2 = __fdiv_rn(__fsub_rn(__fmul_rn(dx, d1y), __fmul_rn(dy, d1x)), det);
            if (t1 >= 0.f && t1 <= 1.f && t2 >= 0.f && t2 <= 1.f)
                atomicOr(&s_cross[t], 1);
        }
    }
    __syncthreads();

    if (tid == 0) {
        float sum = 0.f;
        int crossed = 0;
        for (int t = 0; t < T; ++t) {
            crossed |= s_cross[t];  // cumsum(intersect) >= 1
            float md = s_md[t];
            float l = (md <= DIS_THRESH) ? __fsub_rn(DIS_THRESH, md) : 0.f;
            if (crossed) l = 0.f;
            sum = __fadd_rn(sum, __fmul_rn(l, weight[b * T + t]));
        }
        ws_part[b] = sum;
        __threadfence();
        int old = atomicAdd(cnt_global, 1);
        s_last = (old == B - 1);
    }
    __syncthreads();
    if (!s_last) return;
    __threadfence();  // acquire all ws_part writes

    // ---------------- Phase C: deterministic tree-sum of B partials ----------------
    __shared__ float sm[B];
    if (tid < B) sm[tid] = ld_agent_f(&ws_part[tid]);
    __syncthreads();
    for (int s = B / 2; s > 0; s >>= 1) {
        if (tid < s) sm[tid] = __fadd_rn(sm[tid], sm[tid + s]);
        __syncthreads();
    }
    if (tid == 0) out[0] = __fdiv_rn(sm[0], (float)(B * T));
}

extern "C" void kernel_launch(void* const* d_in, const int* in_sizes, int n_in,
                              void* d_out, int out_size, void* d_ws, size_t ws_size,
                              hipStream_t stream) {
    const float* ego    = (const float*)d_in[0];  // B,T,2
    const float* lanes  = (const float*)d_in[1];  // B,V,P,2
    const float* scores = (const float*)d_in[2];  // B,V,3
    const float* weight = (const float*)d_in[3];  // B,T
    float* out = (float*)d_out;

    char* ws = (char*)d_ws;
    int*   cnt_b      = (int*)(ws + 0);      // 128 ints
    int*   cnt_global = (int*)(ws + 512);
    float* ws_val     = (float*)(ws + 1024);                   // B*T*CHUNKS floats (48 KiB)
    int*   ws_idx     = (int*)(ws + 1024 + B * T * CHUNKS * 4);
    float* ws_part    = (float*)(ws + 1024 + 2 * B * T * CHUNKS * 4);

    hipMemsetAsync(d_ws, 0, 1024, stream);  // zero counters (ws is poisoned 0xAA)
    fused_kernel<<<B * CHUNKS, 256, 0, stream>>>(ego, lanes, scores, weight,
                                                 cnt_b, cnt_global,
                                                 ws_val, ws_idx, ws_part, out);
}

// Round 5
// 92.690 us; speedup vs baseline: 1.4305x; 1.4305x over previous
//
#include <hip/hip_runtime.h>

// Problem constants (from reference)
constexpr int B = 128, T = 12, V = 512, P = 40;
constexpr int CHUNKS = 8;        // V split across 8 blocks per batch
constexpr int VPB = V / CHUNKS;  // 64 v's per block, 4 threads per v
#define MAP_THRESH 0.5f
#define DIS_THRESH 1.0f
#define MASK_FILL  1000000.0f

// NOTE (round 4 post-mortem): grid-fused last-block-finishes with
// __threadfence() cost ~90 us — agent-scope release fences force per-XCD L2
// writeback on gfx950 and dominate everything. Kernel boundaries are the
// cheap sync (~1-2 us in-graph). Keep 3 separate kernels, zero fences.

// transform: x = l*30 - 15 ; y = l*60 - 30  (two-step rounding, no FMA, to match np)
__device__ __forceinline__ float txf(float l) { return __fadd_rn(__fmul_rn(l, 30.0f), -15.0f); }
__device__ __forceinline__ float tyf(float l) { return __fadd_rn(__fmul_rn(l, 60.0f), -30.0f); }

// block-uniform float -> SGPR (keeps the hot loop free of LDS re-reads)
__device__ __forceinline__ float rfl(float x) {
    return __int_as_float(__builtin_amdgcn_readfirstlane(__float_as_int(x)));
}

// ---------------- K1: per (b,chunk) block -> per-t min+argmin over 64 v's ----------------
// grid = B*CHUNKS = 1024 blocks of 256 (4 threads per v, 10 points each).
__global__ __launch_bounds__(256) void k1_mindist(
    const float* __restrict__ ego,     // B,T,2
    const float* __restrict__ lanes,   // B,V,P,2
    const float* __restrict__ scores,  // B,V,3
    float* __restrict__ ws_val,        // B*T*CHUNKS
    int*   __restrict__ ws_idx)        // B*T*CHUNKS
{
    const int blk = blockIdx.x;
    const int b = blk / CHUNKS, c = blk % CHUNKS;
    const int tid = threadIdx.x;
    const int vl = tid >> 2;   // 0..63  v within chunk
    const int pp = tid & 3;    // point-chunk: float4s {pp, 4+pp, 8+pp, 12+pp, 16+pp}
    const int v = c * VPB + vl;

    __shared__ float s_px[T + 1], s_py[T + 1];
    if (tid == 0) {
        float cx = 0.f, cy = 0.f;
        s_px[0] = 0.f; s_py[0] = 0.f;
        for (int t = 0; t < T; ++t) {  // sequential fp32 cumsum, matches np
            cx = __fadd_rn(cx, ego[(b * T + t) * 2 + 0]);
            cy = __fadd_rn(cy, ego[(b * T + t) * 2 + 1]);
            s_px[t + 1] = cx; s_py[t + 1] = cy;
        }
    }
    __syncthreads();

    // block-uniform trajectory -> SGPRs
    float px[T], py[T];
#pragma unroll
    for (int t = 0; t < T; ++t) { px[t] = rfl(s_px[t + 1]); py[t] = rfl(s_py[t + 1]); }

    float minsq[T];
    const bool masked = scores[(size_t)(b * V + v) * 3 + 2] < MAP_THRESH;  // not_bound
    if (masked) {
        // all P points are exactly (1e6, 1e6)
#pragma unroll
        for (int t = 0; t < T; ++t) {
            float dx = __fsub_rn(px[t], MASK_FILL);
            float dy = __fsub_rn(py[t], MASK_FILL);
            minsq[t] = __fadd_rn(__fmul_rn(dx, dx), __fmul_rn(dy, dy));
        }
    } else {
#pragma unroll
        for (int t = 0; t < T; ++t) minsq[t] = 3.4e38f;
        const float4* lp = (const float4*)(lanes + (size_t)(b * V + v) * P * 2);
#pragma unroll
        for (int j = 0; j < 5; ++j) {   // 5 float4 loads, contiguous per 4-thread group
            float4 f = lp[4 * j + pp];
            float x0 = txf(f.x), y0 = tyf(f.y);
            float x1 = txf(f.z), y1 = tyf(f.w);
#pragma unroll
            for (int t = 0; t < T; ++t) {
                float dx = __fsub_rn(px[t], x0);
                float dy = __fsub_rn(py[t], y0);
                float d2 = __fadd_rn(__fmul_rn(dx, dx), __fmul_rn(dy, dy));
                minsq[t] = fminf(minsq[t], d2);
                dx = __fsub_rn(px[t], x1);
                dy = __fsub_rn(py[t], y1);
                d2 = __fadd_rn(__fmul_rn(dx, dx), __fmul_rn(dy, dy));
                minsq[t] = fminf(minsq[t], d2);
            }
        }
    }

    // combine the 4 point-chunks of each v (adjacent lanes, in-wave)
#pragma unroll
    for (int t = 0; t < T; ++t) {
        minsq[t] = fminf(minsq[t], __shfl_xor(minsq[t], 1));
        minsq[t] = fminf(minsq[t], __shfl_xor(minsq[t], 2));
    }

    // sqrt is monotone under RN: sqrt(min) == min(sqrt); compare sqrt'd values
    // so the v-argmin order matches the reference's argmin over norms.
    __shared__ float rv[T][VPB];
    __shared__ int   ri[T][VPB];
    if (pp == 0) {
#pragma unroll
        for (int t = 0; t < T; ++t) { rv[t][vl] = sqrtf(minsq[t]); ri[t][vl] = v; }
    }
    __syncthreads();
    for (int s = VPB / 2; s > 0; s >>= 1) {
        if (tid < s) {
#pragma unroll
            for (int t = 0; t < T; ++t) {
                float v1 = rv[t][tid + s]; int i1 = ri[t][tid + s];
                float v0 = rv[t][tid];     int i0 = ri[t][tid];
                if (v1 < v0 || (v1 == v0 && i1 < i0)) { rv[t][tid] = v1; ri[t][tid] = i1; }
            }
        }
        __syncthreads();
    }
    if (tid < T) {
        ws_val[(b * T + tid) * CHUNKS + c] = rv[tid][0];
        ws_idx[(b * T + tid) * CHUNKS + c] = ri[tid][0];
    }
}

// ---------------- K2: per b -> combine chunks, intersections, weighted sum ----------------
__global__ __launch_bounds__(128) void k2_loss(
    const float* __restrict__ ego,
    const float* __restrict__ lanes,
    const float* __restrict__ scores,
    const float* __restrict__ weight,  // B,T
    const float* __restrict__ ws_val,
    const int*   __restrict__ ws_idx,
    float* __restrict__ ws_part)       // B
{
    const int b = blockIdx.x;
    const int tid = threadIdx.x;
    __shared__ float s_px[T + 1], s_py[T + 1];
    __shared__ float s_md[T];
    __shared__ int   s_vm[T];
    __shared__ int   s_cross[T];
    if (tid == 0) {
        float cx = 0.f, cy = 0.f; s_px[0] = 0.f; s_py[0] = 0.f;
        for (int t = 0; t < T; ++t) {
            cx = __fadd_rn(cx, ego[(b * T + t) * 2 + 0]);
            cy = __fadd_rn(cy, ego[(b * T + t) * 2 + 1]);
            s_px[t + 1] = cx; s_py[t + 1] = cy;
        }
    }
    if (tid < T) {
        float v0 = ws_val[(b * T + tid) * CHUNKS + 0];
        int   i0 = ws_idx[(b * T + tid) * CHUNKS + 0];
        for (int cc = 1; cc < CHUNKS; ++cc) {  // ascending -> strict < keeps first index
            float v1 = ws_val[(b * T + tid) * CHUNKS + cc];
            int   i1 = ws_idx[(b * T + tid) * CHUNKS + cc];
            if (v1 < v0) { v0 = v1; i0 = i1; }
        }
        s_md[tid] = v0; s_vm[tid] = i0;
        s_cross[tid] = 0;
    }
    __syncthreads();

    for (int w = tid; w < T * (P - 1); w += 128) {
        int t = w / (P - 1), p = w % (P - 1);
        int vw = s_vm[t];
        // masked lane -> all points identical -> det == 0 -> never intersects
        if (scores[(size_t)(b * V + vw) * 3 + 2] < MAP_THRESH) continue;
        const float* lp = lanes + (size_t)(b * V + vw) * P * 2 + (size_t)p * 2;
        float bx0 = txf(lp[0]), by0 = tyf(lp[1]);
        float bx1 = txf(lp[2]), by1 = tyf(lp[3]);
        float sx = s_px[t],     sy = s_py[t];      // starts[t]
        float ex = s_px[t + 1], ey = s_py[t + 1];  // pred[t]
        float d1x = __fsub_rn(ex, sx),  d1y = __fsub_rn(ey, sy);
        float d2x = __fsub_rn(bx1, bx0), d2y = __fsub_rn(by1, by0);
        float det = __fsub_rn(__fmul_rn(d1x, d2y), __fmul_rn(d2x, d1y));
        if (det != 0.0f) {
            float dx = __fsub_rn(bx0, sx), dy = __fsub_rn(by0, sy);
            float t1 = __fdiv_rn(__fsub_rn(__fmul_rn(dx, d2y), __fmul_rn(dy, d2x)), det);
            float t2 = __fdiv_rn(__fsub_rn(__fmul_rn(dx, d1y), __fmul_rn(dy, d1x)), det);
            if (t1 >= 0.f && t1 <= 1.f && t2 >= 0.f && t2 <= 1.f)
                atomicOr(&s_cross[t], 1);  // LDS atomic, block-local
        }
    }
    __syncthreads();

    if (tid == 0) {
        float sum = 0.f;
        int crossed = 0;
        for (int t = 0; t < T; ++t) {
            crossed |= s_cross[t];  // cumsum(intersect) >= 1
            float md = s_md[t];
            float l = (md <= DIS_THRESH) ? __fsub_rn(DIS_THRESH, md) : 0.f;
            if (crossed) l = 0.f;
            sum = __fadd_rn(sum, __fmul_rn(l, weight[b * T + t]));
        }
        ws_part[b] = sum;
    }
}

// ---------------- K3: deterministic tree-sum of B partials ----------------
__global__ __launch_bounds__(128) void k3_reduce(
    const float* __restrict__ ws_part, float* __restrict__ out)
{
    __shared__ float sm[B];
    const int tid = threadIdx.x;
    sm[tid] = ws_part[tid];
    __syncthreads();
    for (int s = B / 2; s > 0; s >>= 1) {
        if (tid < s) sm[tid] = __fadd_rn(sm[tid], sm[tid + s]);
        __syncthreads();
    }
    if (tid == 0) out[0] = __fdiv_rn(sm[0], (float)(B * T));
}

extern "C" void kernel_launch(void* const* d_in, const int* in_sizes, int n_in,
                              void* d_out, int out_size, void* d_ws, size_t ws_size,
                              hipStream_t stream) {
    const float* ego    = (const float*)d_in[0];  // B,T,2
    const float* lanes  = (const float*)d_in[1];  // B,V,P,2
    const float* scores = (const float*)d_in[2];  // B,V,3
    const float* weight = (const float*)d_in[3];  // B,T
    float* out = (float*)d_out;

    float* ws_val  = (float*)d_ws;                        // B*T*CHUNKS floats
    int*   ws_idx  = (int*)d_ws + B * T * CHUNKS;         // B*T*CHUNKS ints
    float* ws_part = (float*)d_ws + 2 * B * T * CHUNKS;   // B floats

    k1_mindist<<<B * CHUNKS, 256, 0, stream>>>(ego, lanes, scores, ws_val, ws_idx);
    k2_loss<<<B, 128, 0, stream>>>(ego, lanes, scores, weight, ws_val, ws_idx, ws_part);
    k3_reduce<<<1, 128, 0, stream>>>(ws_part, out);
}

// Round 6
// 87.526 us; speedup vs baseline: 1.5149x; 1.0590x over previous
//
#include <hip/hip_runtime.h>

// Problem constants (from reference)
constexpr int B = 128, T = 12, V = 512, P = 40;
constexpr int CHUNKS = 8;        // V split across 8 blocks per batch
constexpr int VPB = V / CHUNKS;  // 64 v's per block, 4 threads per v
#define MAP_THRESH 0.5f
#define DIS_THRESH 1.0f
#define MASK_FILL  1000000.0f

// Round-4 lesson: agent-scope fences (~90 us) >> kernel boundaries (~2 us).
// Round-5 lesson: 3 kernels + gaps cost ~28 us; consolidate to 2 dispatches
// with a fence-free single-location packed atomic for the final reduce.

// transform: x = l*30 - 15 ; y = l*60 - 30  (two-step rounding, no FMA, to match np)
__device__ __forceinline__ float txf(float l) { return __fadd_rn(__fmul_rn(l, 30.0f), -15.0f); }
__device__ __forceinline__ float tyf(float l) { return __fadd_rn(__fmul_rn(l, 60.0f), -30.0f); }

// block-uniform float -> SGPR (keeps the hot loop free of LDS re-reads)
__device__ __forceinline__ float rfl(float x) {
    return __int_as_float(__builtin_amdgcn_readfirstlane(__float_as_int(x)));
}

#define FIXED_SCALE 1099511627776.0   /* 2^40 */

// ---------------- K1: per (b,chunk) block -> per-t min+argmin over 64 v's ----------------
// grid = B*CHUNKS = 1024 blocks of 256 (4 threads per v, 10 points each).
__global__ __launch_bounds__(256) void k1_mindist(
    const float* __restrict__ ego,     // B,T,2
    const float* __restrict__ lanes,   // B,V,P,2
    const float* __restrict__ scores,  // B,V,3
    float* __restrict__ ws_val,        // B*T*CHUNKS
    int*   __restrict__ ws_idx,        // B*T*CHUNKS
    unsigned long long* __restrict__ acc)  // zeroed here for k2
{
    const int blk = blockIdx.x;
    const int b = blk / CHUNKS, c = blk % CHUNKS;
    const int tid = threadIdx.x;
    const int vl = tid >> 2;   // 0..63  v within chunk
    const int pp = tid & 3;    // point-chunk: float4s {pp, 4+pp, 8+pp, 12+pp, 16+pp}
    const int v = c * VPB + vl;

    if (blk == 0 && tid == 0) *acc = 0ULL;  // visible to k2 via kernel boundary

    __shared__ float s_px[T + 1], s_py[T + 1];
    if (tid == 0) {
        float cx = 0.f, cy = 0.f;
        s_px[0] = 0.f; s_py[0] = 0.f;
        for (int t = 0; t < T; ++t) {  // sequential fp32 cumsum, matches np
            cx = __fadd_rn(cx, ego[(b * T + t) * 2 + 0]);
            cy = __fadd_rn(cy, ego[(b * T + t) * 2 + 1]);
            s_px[t + 1] = cx; s_py[t + 1] = cy;
        }
    }
    __syncthreads();

    // block-uniform trajectory -> SGPRs
    float px[T], py[T];
#pragma unroll
    for (int t = 0; t < T; ++t) { px[t] = rfl(s_px[t + 1]); py[t] = rfl(s_py[t + 1]); }

    float minsq[T];
    const bool masked = scores[(size_t)(b * V + v) * 3 + 2] < MAP_THRESH;  // not_bound
    if (masked) {
        // all P points are exactly (1e6, 1e6)
#pragma unroll
        for (int t = 0; t < T; ++t) {
            float dx = __fsub_rn(px[t], MASK_FILL);
            float dy = __fsub_rn(py[t], MASK_FILL);
            minsq[t] = __fadd_rn(__fmul_rn(dx, dx), __fmul_rn(dy, dy));
        }
    } else {
#pragma unroll
        for (int t = 0; t < T; ++t) minsq[t] = 3.4e38f;
        const float4* lp = (const float4*)(lanes + (size_t)(b * V + v) * P * 2);
#pragma unroll
        for (int j = 0; j < 5; ++j) {   // 5 float4 loads, contiguous per 4-thread group
            float4 f = lp[4 * j + pp];
            float x0 = txf(f.x), y0 = tyf(f.y);
            float x1 = txf(f.z), y1 = tyf(f.w);
#pragma unroll
            for (int t = 0; t < T; ++t) {
                float dx = __fsub_rn(px[t], x0);
                float dy = __fsub_rn(py[t], y0);
                float d2 = __fadd_rn(__fmul_rn(dx, dx), __fmul_rn(dy, dy));
                minsq[t] = fminf(minsq[t], d2);
                dx = __fsub_rn(px[t], x1);
                dy = __fsub_rn(py[t], y1);
                d2 = __fadd_rn(__fmul_rn(dx, dx), __fmul_rn(dy, dy));
                minsq[t] = fminf(minsq[t], d2);
            }
        }
    }

    // combine the 4 point-chunks of each v (adjacent lanes, in-wave)
#pragma unroll
    for (int t = 0; t < T; ++t) {
        minsq[t] = fminf(minsq[t], __shfl_xor(minsq[t], 1));
        minsq[t] = fminf(minsq[t], __shfl_xor(minsq[t], 2));
    }

    // sqrt is monotone under RN: sqrt(min) == min(sqrt); compare sqrt'd values
    // so the v-argmin order matches the reference's argmin over norms.
    float sd[T]; int vidx[T];
#pragma unroll
    for (int t = 0; t < T; ++t) { sd[t] = sqrtf(minsq[t]); vidx[t] = v; }

    // in-wave butterfly over the 16 v's of this wave: lexicographic (val, idx)
    // min is associative+commutative -> first-index tie rule preserved.
#pragma unroll
    for (int lvl = 4; lvl <= 32; lvl <<= 1) {
#pragma unroll
        for (int t = 0; t < T; ++t) {
            float ov = __shfl_xor(sd[t], lvl);
            int   oi = __shfl_xor(vidx[t], lvl);
            if (ov < sd[t] || (ov == sd[t] && oi < vidx[t])) { sd[t] = ov; vidx[t] = oi; }
        }
    }

    // cross-wave: wave w covers ascending v range -> ascending combine keeps first index
    __shared__ float wv[T][4];
    __shared__ int   wi[T][4];
    if ((tid & 63) == 0) {
        int w = tid >> 6;
#pragma unroll
        for (int t = 0; t < T; ++t) { wv[t][w] = sd[t]; wi[t][w] = vidx[t]; }
    }
    __syncthreads();
    if (tid < T) {
        float v0 = wv[tid][0]; int i0 = wi[tid][0];
#pragma unroll
        for (int w = 1; w < 4; ++w) {
            float v1 = wv[tid][w]; int i1 = wi[tid][w];
            if (v1 < v0) { v0 = v1; i0 = i1; }  // strict < keeps first index
        }
        ws_val[(b * T + tid) * CHUNKS + c] = v0;
        ws_idx[(b * T + tid) * CHUNKS + c] = i0;
    }
}

// ---------------- K2: per b -> combine chunks, intersections, weighted sum,
//                  fence-free packed-atomic global reduce ----------------
__global__ __launch_bounds__(256) void k2_loss(
    const float* __restrict__ ego,
    const float* __restrict__ lanes,
    const float* __restrict__ scores,
    const float* __restrict__ weight,  // B,T
    const float* __restrict__ ws_val,
    const int*   __restrict__ ws_idx,
    unsigned long long* __restrict__ acc,
    float* __restrict__ out)
{
    const int b = blockIdx.x;
    const int tid = threadIdx.x;
    __shared__ float s_px[T + 1], s_py[T + 1];
    __shared__ float s_sv[T][CHUNKS];
    __shared__ int   s_si[T][CHUNKS];
    __shared__ float s_md[T];
    __shared__ int   s_vm[T];
    __shared__ int   s_cross[T];
    if (tid < T * CHUNKS) {  // 96 threads: parallel chunk-minima load
        int t = tid >> 3, cc = tid & 7;
        s_sv[t][cc] = ws_val[(b * T + t) * CHUNKS + cc];
        s_si[t][cc] = ws_idx[(b * T + t) * CHUNKS + cc];
    } else if (tid == 96) {
        float cx = 0.f, cy = 0.f; s_px[0] = 0.f; s_py[0] = 0.f;
        for (int t = 0; t < T; ++t) {
            cx = __fadd_rn(cx, ego[(b * T + t) * 2 + 0]);
            cy = __fadd_rn(cy, ego[(b * T + t) * 2 + 1]);
            s_px[t + 1] = cx; s_py[t + 1] = cy;
        }
    } else if (tid >= 128 && tid < 128 + T) {
        s_cross[tid - 128] = 0;
    }
    __syncthreads();
    if (tid < T) {
        float v0 = s_sv[tid][0]; int i0 = s_si[tid][0];
#pragma unroll
        for (int cc = 1; cc < CHUNKS; ++cc) {  // ascending -> strict < keeps first index
            float v1 = s_sv[tid][cc]; int i1 = s_si[tid][cc];
            if (v1 < v0) { v0 = v1; i0 = i1; }
        }
        s_md[tid] = v0; s_vm[tid] = i0;
    }
    __syncthreads();

    for (int w = tid; w < T * (P - 1); w += 256) {
        int t = w / (P - 1), p = w % (P - 1);
        int vw = s_vm[t];
        // masked lane -> all points identical -> det == 0 -> never intersects
        if (scores[(size_t)(b * V + vw) * 3 + 2] < MAP_THRESH) continue;
        const float* lp = lanes + (size_t)(b * V + vw) * P * 2 + (size_t)p * 2;
        float bx0 = txf(lp[0]), by0 = tyf(lp[1]);
        float bx1 = txf(lp[2]), by1 = tyf(lp[3]);
        float sx = s_px[t],     sy = s_py[t];      // starts[t]
        float ex = s_px[t + 1], ey = s_py[t + 1];  // pred[t]
        float d1x = __fsub_rn(ex, sx),  d1y = __fsub_rn(ey, sy);
        float d2x = __fsub_rn(bx1, bx0), d2y = __fsub_rn(by1, by0);
        float det = __fsub_rn(__fmul_rn(d1x, d2y), __fmul_rn(d2x, d1y));
        if (det != 0.0f) {
            float dx = __fsub_rn(bx0, sx), dy = __fsub_rn(by0, sy);
            float t1 = __fdiv_rn(__fsub_rn(__fmul_rn(dx, d2y), __fmul_rn(dy, d2x)), det);
            float t2 = __fdiv_rn(__fsub_rn(__fmul_rn(dx, d1y), __fmul_rn(dy, d1x)), det);
            if (t1 >= 0.f && t1 <= 1.f && t2 >= 0.f && t2 <= 1.f)
                atomicOr(&s_cross[t], 1);  // LDS atomic, block-local
        }
    }
    __syncthreads();

    if (tid == 0) {
        float sum = 0.f;
        int crossed = 0;
        for (int t = 0; t < T; ++t) {
            crossed |= s_cross[t];  // cumsum(intersect) >= 1
            float md = s_md[t];
            float l = (md <= DIS_THRESH) ? __fsub_rn(DIS_THRESH, md) : 0.f;
            if (crossed) l = 0.f;
            sum = __fadd_rn(sum, __fmul_rn(l, weight[b * T + t]));
        }
        // Fence-free deterministic global reduce: fixed-point partial (<=2^44)
        // in bits [0,52), block count in bits [52,...). Single atomic location
        // -> integer sum is order-independent; the 128th arriver sees the
        // exact total in old+pk and finalizes.
        unsigned long long q  = (unsigned long long)((double)sum * FIXED_SCALE + 0.5);
        unsigned long long pk = q + (1ULL << 52);
        unsigned long long old = atomicAdd(acc, pk);
        if ((old >> 52) == (unsigned long long)(B - 1)) {
            unsigned long long tot = (old + pk) & ((1ULL << 52) - 1);
            out[0] = (float)((double)tot * (1.0 / FIXED_SCALE) / (double)(B * T));
        }
    }
}

extern "C" void kernel_launch(void* const* d_in, const int* in_sizes, int n_in,
                              void* d_out, int out_size, void* d_ws, size_t ws_size,
                              hipStream_t stream) {
    const float* ego    = (const float*)d_in[0];  // B,T,2
    const float* lanes  = (const float*)d_in[1];  // B,V,P,2
    const float* scores = (const float*)d_in[2];  // B,V,3
    const float* weight = (const float*)d_in[3];  // B,T
    float* out = (float*)d_out;

    float* ws_val = (float*)d_ws;                      // B*T*CHUNKS floats
    int*   ws_idx = (int*)d_ws + B * T * CHUNKS;       // B*T*CHUNKS ints
    unsigned long long* acc =
        (unsigned long long*)((char*)d_ws + (size_t)2 * B * T * CHUNKS * 4);  // 8B aligned

    k1_mindist<<<B * CHUNKS, 256, 0, stream>>>(ego, lanes, scores, ws_val, ws_idx, acc);
    k2_loss<<<B, 256, 0, stream>>>(ego, lanes, scores, weight, ws_val, ws_idx, acc, out);
}